// Round 6
// baseline (146.401 us; speedup 1.0000x reference)
//
#include <hip/hip_runtime.h>
#include <hip/hip_bf16.h>
#include <stdint.h>

typedef __bf16 bf16x8 __attribute__((ext_vector_type(8)));
typedef float f32x4 __attribute__((ext_vector_type(4)));
typedef unsigned short us4v __attribute__((ext_vector_type(4)));
typedef unsigned short us8v __attribute__((ext_vector_type(8)));

#define B_   2
#define T_   2048
#define C_   1024
#define NH_  16
#define HD_  64

__device__ __forceinline__ unsigned short f2bf(float f) {
  unsigned int u = __builtin_bit_cast(unsigned int, f);
  u += 0x7fffu + ((u >> 16) & 1u);           // RNE
  return (unsigned short)(u >> 16);
}
__device__ __forceinline__ float bf2f(unsigned short u) {
  unsigned int x = ((unsigned int)u) << 16;
  return __builtin_bit_cast(float, x);
}

__device__ __forceinline__ void gload16(const void* g, void* l) {
  __builtin_amdgcn_global_load_lds(
      (const __attribute__((address_space(1))) unsigned int*)g,
      (__attribute__((address_space(3))) unsigned int*)l, 16, 0, 0);
}

__device__ __forceinline__ f32x4 mfma16(bf16x8 a, bf16x8 b, f32x4 c) {
  return __builtin_amdgcn_mfma_f32_16x16x32_bf16(a, b, c, 0, 0, 0);
}

// ---------------- cast / transpose ----------------
__global__ __launch_bounds__(256) void cast_x_kernel(const float4* __restrict__ in,
                                                     us4v* __restrict__ out) {
  int i = blockIdx.x * 256 + threadIdx.x;
  float4 f = in[i];
  us4v o; o[0] = f2bf(f.x); o[1] = f2bf(f.y); o[2] = f2bf(f.z); o[3] = f2bf(f.w);
  out[i] = o;
}

// w: (K x N) fp32 row-major  ->  wT: (N x K) bf16 row-major
__global__ __launch_bounds__(256) void transpose_cast_kernel(const float* __restrict__ w,
                                                             unsigned short* __restrict__ wT,
                                                             int K, int N) {
  __shared__ float tile[32][33];
  int n0 = blockIdx.x * 32, k0 = blockIdx.y * 32;
  int tx = threadIdx.x, ty = threadIdx.y;   // 32 x 8
  #pragma unroll
  for (int i = 0; i < 4; ++i)
    tile[ty + 8*i][tx] = w[(size_t)(k0 + ty + 8*i) * N + n0 + tx];
  __syncthreads();
  #pragma unroll
  for (int i = 0; i < 4; ++i)
    wT[(size_t)(n0 + ty + 8*i) * K + k0 + tx] = f2bf(tile[tx][ty + 8*i]);
}

// ---------------- GEMM core (verified round 0) ----------------
__device__ __forceinline__ void gemm_core(const unsigned short* __restrict__ A,
                                          const unsigned short* __restrict__ Bt,
                                          int K, int m0, int n0,
                                          unsigned short* lA, unsigned short* lB,
                                          f32x4 acc[4][4]) {
  const int t = threadIdx.x;
  const int lane = t & 63, w = t >> 6;
  const int wm = w >> 1, wn = w & 1;
  const int g = lane >> 4, r16 = lane & 15;
  #pragma unroll
  for (int i = 0; i < 4; ++i)
    #pragma unroll
    for (int j = 0; j < 4; ++j) acc[i][j] = (f32x4){0.f, 0.f, 0.f, 0.f};

  for (int k0 = 0; k0 < K; k0 += 64) {
    #pragma unroll
    for (int i = 0; i < 4; ++i) {
      int slot = i * 256 + t;
      int r = slot >> 3, p = slot & 7;
      int q = p ^ (r & 7);
      gload16(A  + (size_t)(m0 + r) * K + k0 + q * 8, lA + slot * 8);
      gload16(Bt + (size_t)(n0 + r) * K + k0 + q * 8, lB + slot * 8);
    }
    asm volatile("s_waitcnt vmcnt(0)" ::: "memory");
    __syncthreads();

    bf16x8 af[4][2], bfr[4][2];
    #pragma unroll
    for (int mi = 0; mi < 4; ++mi)
      #pragma unroll
      for (int kk = 0; kk < 2; ++kk) {
        int r = wm * 64 + mi * 16 + r16;
        int ps = (kk * 4 + g) ^ (r & 7);
        af[mi][kk] = *(const bf16x8*)(lA + r * 64 + ps * 8);
      }
    #pragma unroll
    for (int ni = 0; ni < 4; ++ni)
      #pragma unroll
      for (int kk = 0; kk < 2; ++kk) {
        int r = wn * 64 + ni * 16 + r16;
        int ps = (kk * 4 + g) ^ (r & 7);
        bfr[ni][kk] = *(const bf16x8*)(lB + r * 64 + ps * 8);
      }
    #pragma unroll
    for (int mi = 0; mi < 4; ++mi)
      #pragma unroll
      for (int ni = 0; ni < 4; ++ni)
        #pragma unroll
        for (int kk = 0; kk < 2; ++kk)
          acc[mi][ni] = mfma16(af[mi][kk], bfr[ni][kk], acc[mi][ni]);
    __syncthreads();
  }
}

// XCD-aware bijective swizzle of the linear workgroup id (nwg % 8 == 0)
__device__ __forceinline__ int xcd_swz(int flat, int nwg) {
  int cpx = nwg >> 3;
  return (flat & 7) * cpx + (flat >> 3);
}

__global__ __launch_bounds__(256) void gemm_qkv_kernel(const unsigned short* __restrict__ xb,
                                                       const unsigned short* __restrict__ wT,
                                                       unsigned short* __restrict__ qb,
                                                       unsigned short* __restrict__ kb,
                                                       unsigned short* __restrict__ vb) {
  __shared__ unsigned short lA[128 * 64];
  __shared__ unsigned short lB[128 * 64];
  f32x4 acc[4][4];
  const int nbx = 3 * C_ / 128;
  int flat = xcd_swz(blockIdx.y * nbx + blockIdx.x, nbx * ((B_ * T_) / 128));
  const int m0 = (flat / nbx) * 128, n0 = (flat % nbx) * 128;
  gemm_core(xb, wT, C_, m0, n0, lA, lB, acc);
  const int t = threadIdx.x, lane = t & 63, w = t >> 6;
  const int wm = w >> 1, wn = w & 1, g = lane >> 4, r16 = lane & 15;
  #pragma unroll
  for (int mi = 0; mi < 4; ++mi)
    #pragma unroll
    for (int ni = 0; ni < 4; ++ni)
      #pragma unroll
      for (int j = 0; j < 4; ++j) {
        int gm = m0 + wm * 64 + mi * 16 + g * 4 + j;
        int gn = n0 + wn * 64 + ni * 16 + r16;
        int b = gm >> 11, tt = gm & 2047;
        int s = gn >> 10, rem = gn & 1023;
        int h = rem >> 6, d = rem & 63;
        unsigned short val = f2bf(acc[mi][ni][j]);
        size_t idx = ((size_t)(b * NH_ + h) * T_ + tt) * HD_ + d;
        if (s == 0)      qb[idx] = val;
        else if (s == 1) kb[idx] = val;
        else             vb[idx] = val;
      }
}

__global__ __launch_bounds__(256) void gemm_proj_kernel(const unsigned short* __restrict__ ab,
                                                        const unsigned short* __restrict__ wT,
                                                        float* __restrict__ out) {
  __shared__ unsigned short lA[128 * 64];
  __shared__ unsigned short lB[128 * 64];
  f32x4 acc[4][4];
  const int nbx = C_ / 128;
  int flat = xcd_swz(blockIdx.y * nbx + blockIdx.x, nbx * ((B_ * T_) / 128));
  const int m0 = (flat / nbx) * 128, n0 = (flat % nbx) * 128;
  gemm_core(ab, wT, C_, m0, n0, lA, lB, acc);
  const int t = threadIdx.x, lane = t & 63, w = t >> 6;
  const int wm = w >> 1, wn = w & 1, g = lane >> 4, r16 = lane & 15;
  #pragma unroll
  for (int mi = 0; mi < 4; ++mi)
    #pragma unroll
    for (int ni = 0; ni < 4; ++ni)
      #pragma unroll
      for (int j = 0; j < 4; ++j) {
        int gm = m0 + wm * 64 + mi * 16 + g * 4 + j;
        int gn = n0 + wn * 64 + ni * 16 + r16;
        out[(size_t)gm * C_ + gn] = acc[mi][ni][j];
      }
}

// ---------------- Flash attention v6 ----------------
// v5 + K operand moved OFF the LDS pipe: K fragments are loaded directly
// from global (L2-resident) into registers, pipelined one KV-tile ahead.
// Only V transits LDS (conflict-free transposed staging, verified in v5).
// Counted waits: nv issued before kf; top-of-loop waits nv only (vmcnt(8)),
// kf waited (vmcnt(0)) after the barrier, re-issued after QK consumes them.
__global__ __launch_bounds__(512, 4) void attn_kernel(const unsigned short* __restrict__ qb,
                                                      const unsigned short* __restrict__ kb,
                                                      const unsigned short* __restrict__ vb,
                                                      unsigned short* __restrict__ ao) {
  __shared__ unsigned short LDS[8192];   // V0 [0,4096) V1 [4096,8192); epilogue reuses all
  const int pairIdx = blockIdx.x, bh = blockIdx.y;
  const int t = threadIdx.x, lane = t & 63, w = t >> 6;
  const int g = lane >> 4, r16 = lane & 15;
  const int ws = w & 3, sel = w >> 2;
  const int qt0 = (sel ? (31 - pairIdx) : pairIdx) * 64;
  const int myNt = (qt0 >> 6) + 1;
  const int ntMax = 32 - pairIdx;

  const unsigned short* Q  = qb + (size_t)bh * (T_ * HD_);
  const unsigned short* Kp = kb + (size_t)bh * (T_ * HD_);
  const unsigned short* Vp = vb + (size_t)bh * (T_ * HD_);

  // Q fragments (B-operand layout: lane holds Q[q=r16][k-octet g]), pre-scaled 1/8
  bf16x8 qf[2];
  {
    int qrow = qt0 + ws * 16 + r16;
    #pragma unroll
    for (int kk = 0; kk < 2; ++kk) {
      us8v raw = *(const us8v*)(Q + (size_t)qrow * HD_ + kk * 32 + g * 8);
      bf16x8 qv;
      #pragma unroll
      for (int j = 0; j < 8; ++j) qv[j] = (__bf16)(bf2f(raw[j]) * 0.125f);
      qf[kk] = qv;
    }
  }

  f32x4 o[4];
  #pragma unroll
  for (int c = 0; c < 4; ++c) o[c] = (f32x4){0.f, 0.f, 0.f, 0.f};
  float mrun = -__builtin_inff(), lrun = 0.f;

  // V staging constants: wave w owns d-octet w, lane owns kv row `lane`.
  // col'(kv): kv = 32a+16H+4G+E -> col' = 32a+8G+4H+E (bijective per write-step)
  const int colp = (lane & 32) | ((lane & 12) << 1) | ((lane >> 2) & 4) | (lane & 3);
  const int cslot = colp >> 3, cwithin = colp & 7;

  // prologue: tile-0 loads (nv FIRST, then kf — counted waits rely on this order)
  us8v nv = *(const us8v*)(Vp + (size_t)lane * HD_ + w * 8);
  bf16x8 kf[4][2];
  #pragma unroll
  for (int c = 0; c < 4; ++c)
    #pragma unroll
    for (int kk = 0; kk < 2; ++kk)
      kf[c][kk] = *(const bf16x8*)(Kp + (size_t)(c * 16 + r16) * HD_ + kk * 32 + g * 8);

  for (int it = 0; it < ntMax; ++it) {
    const int cur = it & 1;
    unsigned short* Vt = LDS + cur * 4096;

    if (it < myNt) { asm volatile("s_waitcnt vmcnt(8)" ::: "memory"); }  // nv ready, kf in flight
    else           { asm volatile("s_waitcnt vmcnt(0)" ::: "memory"); }  // nv only outstanding
    #pragma unroll
    for (int u = 0; u < 8; ++u) {
      int d = w * 8 + u;                       // d&7 == u
      Vt[d * 64 + ((cslot ^ u) << 3) + cwithin] = nv[u];
    }
    __syncthreads();

    f32x4 s4t[4];
    if (it < myNt) {
      asm volatile("s_waitcnt vmcnt(0)" ::: "memory");   // kf(it) ready
      // S^T = K @ Q^T : s4t[c][j] = S[q=r16][kv = it*64 + 16c + 4g + j]
      #pragma unroll
      for (int c = 0; c < 4; ++c) s4t[c] = (f32x4){0.f, 0.f, 0.f, 0.f};
      #pragma unroll
      for (int c = 0; c < 4; ++c)
        #pragma unroll
        for (int kk = 0; kk < 2; ++kk)
          s4t[c] = mfma16(kf[c][kk], qf[kk], s4t[c]);
    }

    // issue next-tile loads (nv first, then kf; kf regs free after QK above)
    if (it + 1 < ntMax)
      nv = *(const us8v*)(Vp + (size_t)((it + 1) * 64 + lane) * HD_ + w * 8);
    if (it + 1 < myNt) {
      const unsigned short* Kn = Kp + (size_t)(it + 1) * 64 * HD_;
      #pragma unroll
      for (int c = 0; c < 4; ++c)
        #pragma unroll
        for (int kk = 0; kk < 2; ++kk)
          kf[c][kk] = *(const bf16x8*)(Kn + (size_t)(c * 16 + r16) * HD_ + kk * 32 + g * 8);
    }

    if (it < myNt) {
      if (it == myNt - 1) {   // diagonal tile (kv0 == qt0): mask kv_local > q_local
        int qloc = ws * 16 + r16;
        #pragma unroll
        for (int c = 0; c < 4; ++c)
          #pragma unroll
          for (int j = 0; j < 4; ++j)
            if (c * 16 + g * 4 + j > qloc) s4t[c][j] = -1e30f;
      }
      // online softmax: row q=r16 lane-local across 16 regs + 4 lanes (xor 16,32)
      float mx = -1e30f;
      #pragma unroll
      for (int c = 0; c < 4; ++c)
        #pragma unroll
        for (int j = 0; j < 4; ++j) mx = fmaxf(mx, s4t[c][j]);
      mx = fmaxf(mx, __shfl_xor(mx, 16));
      mx = fmaxf(mx, __shfl_xor(mx, 32));
      float mn = fmaxf(mrun, mx);
      float alpha = __expf(mrun - mn);
      mrun = mn;
      float rs = 0.f;
      #pragma unroll
      for (int c = 0; c < 4; ++c)
        #pragma unroll
        for (int j = 0; j < 4; ++j) {
          float p = __expf(s4t[c][j] - mn);
          s4t[c][j] = p;
          rs += p;
        }
      rs += __shfl_xor(rs, 16);
      rs += __shfl_xor(rs, 32);
      lrun = lrun * alpha + rs;
      #pragma unroll
      for (int c = 0; c < 4; ++c)
        #pragma unroll
        for (int j = 0; j < 4; ++j) o[c][j] *= alpha;

      // P^T fragments in-register (B-operand): p[4h+e] = s4t[2kk+h][e]
      bf16x8 pf[2];
      #pragma unroll
      for (int kk = 0; kk < 2; ++kk) {
        bf16x8 p;
        #pragma unroll
        for (int j = 0; j < 4; ++j) {
          p[j]     = (__bf16)s4t[2 * kk][j];
          p[4 + j] = (__bf16)s4t[2 * kk + 1][j];
        }
        pf[kk] = p;
      }
      // O^T += V^T @ P^T : A-fragment = swizzled b128 from Vt
      #pragma unroll
      for (int c = 0; c < 4; ++c) {
        int rv = c * 16 + r16;
        #pragma unroll
        for (int kk = 0; kk < 2; ++kk) {
          int slot = (4 * kk + g) ^ (r16 & 7);
          bf16x8 vf = *(const bf16x8*)(Vt + rv * 64 + slot * 8);
          o[c] = mfma16(vf, pf[kk], o[c]);
        }
      }
    }
  }

  __syncthreads();   // all waves done with V buffers before epilogue reuse

  // epilogue: O[q=r16][d=16c+4g+j] / lrun -> per-wave LDS transpose -> store
  unsigned short* ep = LDS + w * 1024;
  float inv = 1.f / lrun;
  #pragma unroll
  for (int c = 0; c < 4; ++c) {
    us4v pk;
    #pragma unroll
    for (int j = 0; j < 4; ++j) pk[j] = f2bf(o[c][j] * inv);
    int slot = (4 * c + g) ^ r16;
    *(us4v*)(ep + r16 * 64 + slot * 4) = pk;
  }
  asm volatile("s_waitcnt lgkmcnt(0)" ::: "memory");
  __builtin_amdgcn_sched_barrier(0);
  {
    int q = lane >> 2, seg = lane & 3;
    us4v a0 = *(const us4v*)(ep + q * 64 + (((seg * 4 + 0) ^ q) & 15) * 4);
    us4v a1 = *(const us4v*)(ep + q * 64 + (((seg * 4 + 1) ^ q) & 15) * 4);
    us4v a2 = *(const us4v*)(ep + q * 64 + (((seg * 4 + 2) ^ q) & 15) * 4);
    us4v a3 = *(const us4v*)(ep + q * 64 + (((seg * 4 + 3) ^ q) & 15) * 4);
    us8v o0 = {a0[0],a0[1],a0[2],a0[3],a1[0],a1[1],a1[2],a1[3]};
    us8v o1 = {a2[0],a2[1],a2[2],a2[3],a3[0],a3[1],a3[2],a3[3]};
    size_t rowg = (size_t)(bh >> 4) * T_ + qt0 + ws * 16 + q;
    int colg = (bh & 15) * 64 + seg * 16;
    *(us8v*)(ao + rowg * C_ + colg)     = o0;
    *(us8v*)(ao + rowg * C_ + colg + 8) = o1;
  }
}

// ---------------- launch ----------------
extern "C" void kernel_launch(void* const* d_in, const int* in_sizes, int n_in,
                              void* d_out, int out_size, void* d_ws, size_t ws_size,
                              hipStream_t stream) {
  const float* x      = (const float*)d_in[0];
  const float* w_qkv  = (const float*)d_in[1];
  const float* w_proj = (const float*)d_in[2];
  float* out = (float*)d_out;
  char* ws = (char*)d_ws;

  unsigned short* xb     = (unsigned short*)(ws);              // 8 MB (reused as ao)
  unsigned short* wqkvT  = (unsigned short*)(ws + 8388608);    // 6 MB
  unsigned short* wprojT = (unsigned short*)(ws + 14680064);   // 2 MB
  unsigned short* qb     = (unsigned short*)(ws + 16777216);   // 8 MB
  unsigned short* kb     = (unsigned short*)(ws + 25165824);   // 8 MB
  unsigned short* vb     = (unsigned short*)(ws + 33554432);   // 8 MB
  unsigned short* ao     = xb;

  cast_x_kernel<<<4096, 256, 0, stream>>>((const float4*)x, (us4v*)xb);
  transpose_cast_kernel<<<dim3(3 * C_ / 32, C_ / 32), dim3(32, 8), 0, stream>>>(
      w_qkv, wqkvT, C_, 3 * C_);
  transpose_cast_kernel<<<dim3(C_ / 32, C_ / 32), dim3(32, 8), 0, stream>>>(
      w_proj, wprojT, C_, C_);
  gemm_qkv_kernel<<<dim3(3 * C_ / 128, (B_ * T_) / 128), 256, 0, stream>>>(
      xb, wqkvT, qb, kb, vb);
  attn_kernel<<<dim3(16, 32), 512, 0, stream>>>(qb, kb, vb, ao);
  gemm_proj_kernel<<<dim3(C_ / 128, (B_ * T_) / 128), 256, 0, stream>>>(
      ao, wprojT, out);
}

// Round 7
// 126.734 us; speedup vs baseline: 1.1552x; 1.1552x over previous
//
#include <hip/hip_runtime.h>
#include <hip/hip_bf16.h>
#include <stdint.h>

typedef __bf16 bf16x8 __attribute__((ext_vector_type(8)));
typedef float f32x4 __attribute__((ext_vector_type(4)));
typedef unsigned short us4v __attribute__((ext_vector_type(4)));
typedef unsigned short us8v __attribute__((ext_vector_type(8)));

#define B_   2
#define T_   2048
#define C_   1024
#define NH_  16
#define HD_  64

__device__ __forceinline__ unsigned short f2bf(float f) {
  unsigned int u = __builtin_bit_cast(unsigned int, f);
  u += 0x7fffu + ((u >> 16) & 1u);           // RNE
  return (unsigned short)(u >> 16);
}
__device__ __forceinline__ float bf2f(unsigned short u) {
  unsigned int x = ((unsigned int)u) << 16;
  return __builtin_bit_cast(float, x);
}

__device__ __forceinline__ void gload16(const void* g, void* l) {
  __builtin_amdgcn_global_load_lds(
      (const __attribute__((address_space(1))) unsigned int*)g,
      (__attribute__((address_space(3))) unsigned int*)l, 16, 0, 0);
}

__device__ __forceinline__ f32x4 mfma16(bf16x8 a, bf16x8 b, f32x4 c) {
  return __builtin_amdgcn_mfma_f32_16x16x32_bf16(a, b, c, 0, 0, 0);
}

// ---------------- cast / transpose ----------------
__global__ __launch_bounds__(256) void cast_x_kernel(const float4* __restrict__ in,
                                                     us4v* __restrict__ out) {
  int i = blockIdx.x * 256 + threadIdx.x;
  float4 f = in[i];
  us4v o; o[0] = f2bf(f.x); o[1] = f2bf(f.y); o[2] = f2bf(f.z); o[3] = f2bf(f.w);
  out[i] = o;
}

// w: (K x N) fp32 row-major  ->  wT: (N x K) bf16 row-major
__global__ __launch_bounds__(256) void transpose_cast_kernel(const float* __restrict__ w,
                                                             unsigned short* __restrict__ wT,
                                                             int K, int N) {
  __shared__ float tile[32][33];
  int n0 = blockIdx.x * 32, k0 = blockIdx.y * 32;
  int tx = threadIdx.x, ty = threadIdx.y;   // 32 x 8
  #pragma unroll
  for (int i = 0; i < 4; ++i)
    tile[ty + 8*i][tx] = w[(size_t)(k0 + ty + 8*i) * N + n0 + tx];
  __syncthreads();
  #pragma unroll
  for (int i = 0; i < 4; ++i)
    wT[(size_t)(n0 + ty + 8*i) * K + k0 + tx] = f2bf(tile[tx][ty + 8*i]);
}

// ---------------- GEMM core (verified round 0) ----------------
__device__ __forceinline__ void gemm_core(const unsigned short* __restrict__ A,
                                          const unsigned short* __restrict__ Bt,
                                          int K, int m0, int n0,
                                          unsigned short* lA, unsigned short* lB,
                                          f32x4 acc[4][4]) {
  const int t = threadIdx.x;
  const int lane = t & 63, w = t >> 6;
  const int wm = w >> 1, wn = w & 1;
  const int g = lane >> 4, r16 = lane & 15;
  #pragma unroll
  for (int i = 0; i < 4; ++i)
    #pragma unroll
    for (int j = 0; j < 4; ++j) acc[i][j] = (f32x4){0.f, 0.f, 0.f, 0.f};

  for (int k0 = 0; k0 < K; k0 += 64) {
    #pragma unroll
    for (int i = 0; i < 4; ++i) {
      int slot = i * 256 + t;
      int r = slot >> 3, p = slot & 7;
      int q = p ^ (r & 7);
      gload16(A  + (size_t)(m0 + r) * K + k0 + q * 8, lA + slot * 8);
      gload16(Bt + (size_t)(n0 + r) * K + k0 + q * 8, lB + slot * 8);
    }
    asm volatile("s_waitcnt vmcnt(0)" ::: "memory");
    __syncthreads();

    bf16x8 af[4][2], bfr[4][2];
    #pragma unroll
    for (int mi = 0; mi < 4; ++mi)
      #pragma unroll
      for (int kk = 0; kk < 2; ++kk) {
        int r = wm * 64 + mi * 16 + r16;
        int ps = (kk * 4 + g) ^ (r & 7);
        af[mi][kk] = *(const bf16x8*)(lA + r * 64 + ps * 8);
      }
    #pragma unroll
    for (int ni = 0; ni < 4; ++ni)
      #pragma unroll
      for (int kk = 0; kk < 2; ++kk) {
        int r = wn * 64 + ni * 16 + r16;
        int ps = (kk * 4 + g) ^ (r & 7);
        bfr[ni][kk] = *(const bf16x8*)(lB + r * 64 + ps * 8);
      }
    #pragma unroll
    for (int mi = 0; mi < 4; ++mi)
      #pragma unroll
      for (int ni = 0; ni < 4; ++ni)
        #pragma unroll
        for (int kk = 0; kk < 2; ++kk)
          acc[mi][ni] = mfma16(af[mi][kk], bfr[ni][kk], acc[mi][ni]);
    __syncthreads();
  }
}

// XCD-aware bijective swizzle of the linear workgroup id (nwg % 8 == 0)
__device__ __forceinline__ int xcd_swz(int flat, int nwg) {
  int cpx = nwg >> 3;
  return (flat & 7) * cpx + (flat >> 3);
}

__global__ __launch_bounds__(256) void gemm_qkv_kernel(const unsigned short* __restrict__ xb,
                                                       const unsigned short* __restrict__ wT,
                                                       unsigned short* __restrict__ qb,
                                                       unsigned short* __restrict__ kb,
                                                       unsigned short* __restrict__ vb) {
  __shared__ unsigned short lA[128 * 64];
  __shared__ unsigned short lB[128 * 64];
  f32x4 acc[4][4];
  const int nbx = 3 * C_ / 128;
  int flat = xcd_swz(blockIdx.y * nbx + blockIdx.x, nbx * ((B_ * T_) / 128));
  const int m0 = (flat / nbx) * 128, n0 = (flat % nbx) * 128;
  gemm_core(xb, wT, C_, m0, n0, lA, lB, acc);
  const int t = threadIdx.x, lane = t & 63, w = t >> 6;
  const int wm = w >> 1, wn = w & 1, g = lane >> 4, r16 = lane & 15;
  #pragma unroll
  for (int mi = 0; mi < 4; ++mi)
    #pragma unroll
    for (int ni = 0; ni < 4; ++ni)
      #pragma unroll
      for (int j = 0; j < 4; ++j) {
        int gm = m0 + wm * 64 + mi * 16 + g * 4 + j;
        int gn = n0 + wn * 64 + ni * 16 + r16;
        int b = gm >> 11, tt = gm & 2047;
        int s = gn >> 10, rem = gn & 1023;
        int h = rem >> 6, d = rem & 63;
        unsigned short val = f2bf(acc[mi][ni][j]);
        size_t idx = ((size_t)(b * NH_ + h) * T_ + tt) * HD_ + d;
        if (s == 0)      qb[idx] = val;
        else if (s == 1) kb[idx] = val;
        else             vb[idx] = val;
      }
}

__global__ __launch_bounds__(256) void gemm_proj_kernel(const unsigned short* __restrict__ ab,
                                                        const unsigned short* __restrict__ wT,
                                                        float* __restrict__ out) {
  __shared__ unsigned short lA[128 * 64];
  __shared__ unsigned short lB[128 * 64];
  f32x4 acc[4][4];
  const int nbx = C_ / 128;
  int flat = xcd_swz(blockIdx.y * nbx + blockIdx.x, nbx * ((B_ * T_) / 128));
  const int m0 = (flat / nbx) * 128, n0 = (flat % nbx) * 128;
  gemm_core(ab, wT, C_, m0, n0, lA, lB, acc);
  const int t = threadIdx.x, lane = t & 63, w = t >> 6;
  const int wm = w >> 1, wn = w & 1, g = lane >> 4, r16 = lane & 15;
  #pragma unroll
  for (int mi = 0; mi < 4; ++mi)
    #pragma unroll
    for (int ni = 0; ni < 4; ++ni)
      #pragma unroll
      for (int j = 0; j < 4; ++j) {
        int gm = m0 + wm * 64 + mi * 16 + g * 4 + j;
        int gn = n0 + wn * 64 + ni * 16 + r16;
        out[(size_t)gm * C_ + gn] = acc[mi][ni][j];
      }
}

// ---------------- Flash attention v7 ----------------
// Round-5 structure (K via gload_lds, V via conflict-free reg->LDS transpose,
// double-buffered, one barrier/iter) with 32 q-rows per wave: each staged
// kf/vf fragment read feeds TWO MFMAs (halves LDS reads per unit work).
// Block = 256 threads (4 waves), pair (pairIdx, 31-pairIdx) of 64-row q-tiles;
// wave w: sel=w>>1 picks tile, w&1 picks 32-row half; each wave owns 32 rows
// as two 16-row fragment halves h=0,1.
// LDS (us): K0 [0,4096) K1 [4096,8192) V0 [8192,12288) V1 [12288,16384).
__global__ __launch_bounds__(256, 3) void attn_kernel(const unsigned short* __restrict__ qb,
                                                      const unsigned short* __restrict__ kb,
                                                      const unsigned short* __restrict__ vb,
                                                      unsigned short* __restrict__ ao) {
  __shared__ unsigned short LDS[16384];
  const int pairIdx = blockIdx.x, bh = blockIdx.y;
  const int t = threadIdx.x, lane = t & 63, w4 = t >> 6;
  const int g = lane >> 4, r16 = lane & 15;
  const int sel = w4 >> 1, halfsel = w4 & 1;
  const int tileBase = sel ? (31 - pairIdx) : pairIdx;
  const int qt0 = tileBase * 64 + halfsel * 32;
  const int myNt = tileBase + 1;
  const int ntMax = 32 - pairIdx;

  const unsigned short* Q  = qb + (size_t)bh * (T_ * HD_);
  const unsigned short* Kp = kb + (size_t)bh * (T_ * HD_);
  const unsigned short* Vp = vb + (size_t)bh * (T_ * HD_);

  // Q fragments (B-operand: lane holds Q[q=r16][k-octet g]), two halves, pre-scaled 1/8
  bf16x8 qf[2][2];
  #pragma unroll
  for (int h = 0; h < 2; ++h) {
    int qrow = qt0 + h * 16 + r16;
    #pragma unroll
    for (int kk = 0; kk < 2; ++kk) {
      us8v raw = *(const us8v*)(Q + (size_t)qrow * HD_ + kk * 32 + g * 8);
      bf16x8 qv;
      #pragma unroll
      for (int j = 0; j < 8; ++j) qv[j] = (__bf16)(bf2f(raw[j]) * 0.125f);
      qf[h][kk] = qv;
    }
  }

  f32x4 o[2][4];
  #pragma unroll
  for (int h = 0; h < 2; ++h)
    #pragma unroll
    for (int c = 0; c < 4; ++c) o[h][c] = (f32x4){0.f, 0.f, 0.f, 0.f};
  float mrun[2] = {-__builtin_inff(), -__builtin_inff()};
  float lrun[2] = {0.f, 0.f};

  // staging constants
  // K: thread stages slots t and t+256 (row r=slot>>3, swizzled granule)
  const int kr0 = t >> 3,        kp0 = (t & 7) ^ (kr0 & 7);
  const int kr1 = (t + 256) >> 3, kp1 = (t & 7) ^ (kr1 & 7);
  // V: wave w4 owns d-rows [16w4,16w4+16), lane owns kv row `lane`.
  // col'(kv): kv = 32a+16H+4G+E -> col' = 32a+8G+4H+E (bijective per write-step)
  const int colp = (lane & 32) | ((lane & 12) << 1) | ((lane >> 2) & 4) | (lane & 3);
  const int cslot = colp >> 3, cwithin = colp & 7;

  // prologue: tile-0 loads (K DMA then V regs)
  gload16(Kp + (size_t)kr0 * HD_ + kp0 * 8, LDS + t * 8);
  gload16(Kp + (size_t)kr1 * HD_ + kp1 * 8, LDS + (t + 256) * 8);
  us8v nv0 = *(const us8v*)(Vp + (size_t)lane * HD_ + w4 * 16);
  us8v nv1 = *(const us8v*)(Vp + (size_t)lane * HD_ + w4 * 16 + 8);

  for (int it = 0; it < ntMax; ++it) {
    const int cur = it & 1;
    const unsigned short* Kl = LDS + cur * 4096;
    unsigned short* Vt = LDS + 8192 + cur * 4096;

    asm volatile("s_waitcnt vmcnt(0)" ::: "memory");   // K[it] in LDS, V[it] in regs
    #pragma unroll
    for (int u = 0; u < 8; ++u) {
      int d = w4 * 16 + u;                             // d&7 == u
      Vt[d * 64 + ((cslot ^ u) << 3) + cwithin] = nv0[u];
    }
    #pragma unroll
    for (int u = 0; u < 8; ++u) {
      int d = w4 * 16 + 8 + u;                         // d&7 == u
      Vt[d * 64 + ((cslot ^ u) << 3) + cwithin] = nv1[u];
    }
    __syncthreads();

    if (it + 1 < ntMax) {    // issue next-tile loads (land in buf cur^1)
      const int kv0n = (it + 1) * 64;
      unsigned short* Kn = LDS + (cur ^ 1) * 4096;
      gload16(Kp + (size_t)(kv0n + kr0) * HD_ + kp0 * 8, Kn + t * 8);
      gload16(Kp + (size_t)(kv0n + kr1) * HD_ + kp1 * 8, Kn + (t + 256) * 8);
      nv0 = *(const us8v*)(Vp + (size_t)(kv0n + lane) * HD_ + w4 * 16);
      nv1 = *(const us8v*)(Vp + (size_t)(kv0n + lane) * HD_ + w4 * 16 + 8);
    }

    if (it < myNt) {
      // S^T = K @ Q^T : s4t[h][c][j] = S[q = qt0+16h+r16][kv = it*64 + 16c + 4g + j]
      f32x4 s4t[2][4];
      #pragma unroll
      for (int h = 0; h < 2; ++h)
        #pragma unroll
        for (int c = 0; c < 4; ++c) s4t[h][c] = (f32x4){0.f, 0.f, 0.f, 0.f};
      #pragma unroll
      for (int c = 0; c < 4; ++c)
        #pragma unroll
        for (int kk = 0; kk < 2; ++kk) {
          int r = c * 16 + r16;
          int ps = (kk * 4 + g) ^ (r & 7);
          bf16x8 kf = *(const bf16x8*)(Kl + r * 64 + ps * 8);   // 1 read, 2 MFMAs
          s4t[0][c] = mfma16(kf, qf[0][kk], s4t[0][c]);
          s4t[1][c] = mfma16(kf, qf[1][kk], s4t[1][c]);
        }
      if (it == myNt - 1) {   // diagonal tile: mask kv_local > q position in tile
        #pragma unroll
        for (int h = 0; h < 2; ++h) {
          int qloc = halfsel * 32 + h * 16 + r16;
          #pragma unroll
          for (int c = 0; c < 4; ++c)
            #pragma unroll
            for (int j = 0; j < 4; ++j)
              if (c * 16 + g * 4 + j > qloc) s4t[h][c][j] = -1e30f;
        }
      }
      // online softmax per half: row lane-local in 16 regs + 4 lanes (xor 16,32)
      bf16x8 pf[2][2];
      #pragma unroll
      for (int h = 0; h < 2; ++h) {
        float mx = -1e30f;
        #pragma unroll
        for (int c = 0; c < 4; ++c)
          #pragma unroll
          for (int j = 0; j < 4; ++j) mx = fmaxf(mx, s4t[h][c][j]);
        mx = fmaxf(mx, __shfl_xor(mx, 16));
        mx = fmaxf(mx, __shfl_xor(mx, 32));
        float mn = fmaxf(mrun[h], mx);
        float alpha = __expf(mrun[h] - mn);
        mrun[h] = mn;
        float rs = 0.f;
        #pragma unroll
        for (int c = 0; c < 4; ++c)
          #pragma unroll
          for (int j = 0; j < 4; ++j) {
            float p = __expf(s4t[h][c][j] - mn);
            s4t[h][c][j] = p;
            rs += p;
          }
        rs += __shfl_xor(rs, 16);
        rs += __shfl_xor(rs, 32);
        lrun[h] = lrun[h] * alpha + rs;
        #pragma unroll
        for (int c = 0; c < 4; ++c)
          #pragma unroll
          for (int j = 0; j < 4; ++j) o[h][c][j] *= alpha;
        // P^T fragments (B-operand): p[4hh+e] = s4t[h][2kk+hh][e]
        #pragma unroll
        for (int kk = 0; kk < 2; ++kk) {
          bf16x8 p;
          #pragma unroll
          for (int j = 0; j < 4; ++j) {
            p[j]     = (__bf16)s4t[h][2 * kk][j];
            p[4 + j] = (__bf16)s4t[h][2 * kk + 1][j];
          }
          pf[h][kk] = p;
        }
      }
      // O^T += V^T @ P^T : 1 vf read feeds 2 MFMAs
      #pragma unroll
      for (int c = 0; c < 4; ++c) {
        int rv = c * 16 + r16;
        #pragma unroll
        for (int kk = 0; kk < 2; ++kk) {
          int slot = (4 * kk + g) ^ (r16 & 7);
          bf16x8 vf = *(const bf16x8*)(Vt + rv * 64 + slot * 8);
          o[0][c] = mfma16(vf, pf[0][kk], o[0][c]);
          o[1][c] = mfma16(vf, pf[1][kk], o[1][c]);
        }
      }
    }
  }

  // epilogue: dead K buffer, per-wave 1024 us, two 16-row passes
  const int deadK = ((ntMax - 1) & 1) ^ 1;
  unsigned short* ep = LDS + deadK * 4096 + w4 * 1024;
  #pragma unroll
  for (int h = 0; h < 2; ++h) {
    float inv = 1.f / lrun[h];
    #pragma unroll
    for (int c = 0; c < 4; ++c) {
      us4v pk;
      #pragma unroll
      for (int j = 0; j < 4; ++j) pk[j] = f2bf(o[h][c][j] * inv);
      int slot = (4 * c + g) ^ r16;
      *(us4v*)(ep + r16 * 64 + slot * 4) = pk;
    }
    asm volatile("s_waitcnt lgkmcnt(0)" ::: "memory");
    __builtin_amdgcn_sched_barrier(0);
    {
      int q = lane >> 2, seg = lane & 3;
      us4v a0 = *(const us4v*)(ep + q * 64 + (((seg * 4 + 0) ^ q) & 15) * 4);
      us4v a1 = *(const us4v*)(ep + q * 64 + (((seg * 4 + 1) ^ q) & 15) * 4);
      us4v a2 = *(const us4v*)(ep + q * 64 + (((seg * 4 + 2) ^ q) & 15) * 4);
      us4v a3 = *(const us4v*)(ep + q * 64 + (((seg * 4 + 3) ^ q) & 15) * 4);
      us8v o0 = {a0[0],a0[1],a0[2],a0[3],a1[0],a1[1],a1[2],a1[3]};
      us8v o1 = {a2[0],a2[1],a2[2],a2[3],a3[0],a3[1],a3[2],a3[3]};
      size_t rowg = (size_t)(bh >> 4) * T_ + qt0 + h * 16 + q;
      int colg = (bh & 15) * 64 + seg * 16;
      *(us8v*)(ao + rowg * C_ + colg)     = o0;
      *(us8v*)(ao + rowg * C_ + colg + 8) = o1;
    }
    asm volatile("s_waitcnt lgkmcnt(0)" ::: "memory");
    __builtin_amdgcn_sched_barrier(0);
  }
}

// ---------------- launch ----------------
extern "C" void kernel_launch(void* const* d_in, const int* in_sizes, int n_in,
                              void* d_out, int out_size, void* d_ws, size_t ws_size,
                              hipStream_t stream) {
  const float* x      = (const float*)d_in[0];
  const float* w_qkv  = (const float*)d_in[1];
  const float* w_proj = (const float*)d_in[2];
  float* out = (float*)d_out;
  char* ws = (char*)d_ws;

  unsigned short* xb     = (unsigned short*)(ws);              // 8 MB (reused as ao)
  unsigned short* wqkvT  = (unsigned short*)(ws + 8388608);    // 6 MB
  unsigned short* wprojT = (unsigned short*)(ws + 14680064);   // 2 MB
  unsigned short* qb     = (unsigned short*)(ws + 16777216);   // 8 MB
  unsigned short* kb     = (unsigned short*)(ws + 25165824);   // 8 MB
  unsigned short* vb     = (unsigned short*)(ws + 33554432);   // 8 MB
  unsigned short* ao     = xb;

  cast_x_kernel<<<4096, 256, 0, stream>>>((const float4*)x, (us4v*)xb);
  transpose_cast_kernel<<<dim3(3 * C_ / 32, C_ / 32), dim3(32, 8), 0, stream>>>(
      w_qkv, wqkvT, C_, 3 * C_);
  transpose_cast_kernel<<<dim3(C_ / 32, C_ / 32), dim3(32, 8), 0, stream>>>(
      w_proj, wprojT, C_, C_);
  gemm_qkv_kernel<<<dim3(3 * C_ / 128, (B_ * T_) / 128), 256, 0, stream>>>(
      xb, wqkvT, qb, kb, vb);
  attn_kernel<<<dim3(16, 32), 256, 0, stream>>>(qb, kb, vb, ao);
  gemm_proj_kernel<<<dim3(C_ / 128, (B_ * T_) / 128), 256, 0, stream>>>(
      ao, wprojT, out);
}